// Round 6
// baseline (419.015 us; speedup 1.0000x reference)
//
#include <hip/hip_runtime.h>
#include <hip/hip_bf16.h>

typedef __attribute__((ext_vector_type(8))) short short8;
typedef __attribute__((ext_vector_type(4))) unsigned short ushort4_t;
typedef __attribute__((ext_vector_type(4))) float f32x4;

#define CAP_AP 64
#define CAP_PP 128

__device__ __forceinline__ unsigned short f2bf(float f) {
  unsigned u = __float_as_uint(f);
  u += 0x7FFFu + ((u >> 16) & 1u);
  return (unsigned short)(u >> 16);
}

// ===========================================================================
// K1: init map / counters
// ===========================================================================
__global__ __launch_bounds__(256) void k_init(
    int* __restrict__ map, int* __restrict__ cnt_ap, int* __restrict__ cnt_pp,
    int* __restrict__ ccount, int n_aa, int batch)
{
  int i = blockIdx.x * 256 + threadIdx.x;
  if (i < n_aa) map[i] = -1;
  if (i < batch) { cnt_ap[i] = 0; cnt_pp[i] = 0; }
  if (i == 0) *ccount = 0;
}

// ===========================================================================
// K2: histogram + DIRECT bucket-CSR fill (no scan/scatter passes needed).
// ===========================================================================
__global__ __launch_bounds__(256) void k_edges(
    const int* __restrict__ ei_ap, const int* __restrict__ ei_pp,
    int* __restrict__ map, int* __restrict__ cnt_ap, int* __restrict__ cnt_pp,
    int* __restrict__ csr_ap, int* __restrict__ csr_pp,
    int e_ap, int e_pp, int nb_ap, int batch)
{
  int b = blockIdx.x;
  if (b < nb_ap) {
    int e = b * 256 + threadIdx.x;
    if (e < e_ap) {
      int d = ei_ap[e_ap + e];
      if (d < batch) {
        int s = ei_ap[e];
        int pos = atomicAdd(&cnt_ap[d], 1);
        if (pos < CAP_AP) csr_ap[d * CAP_AP + pos] = s;
        map[s] = 1;
      }
    }
  } else {
    int e = (b - nb_ap) * 256 + threadIdx.x;
    if (e < e_pp) {
      int d = ei_pp[e_pp + e];
      if (d < batch) {
        int pos = atomicAdd(&cnt_pp[d], 1);
        if (pos < CAP_PP) csr_pp[d * CAP_PP + pos] = ei_pp[e];
      }
    }
  }
}

// ===========================================================================
// K3: compaction-slot assignment, block-aggregated atomic (1 atomic/block).
// ===========================================================================
__global__ __launch_bounds__(256) void k_assign(
    int* __restrict__ map, int* __restrict__ inv, int* __restrict__ ccount, int n)
{
  __shared__ int wb[4];
  int i = blockIdx.x * 256 + threadIdx.x;
  bool need = (i < n) && (map[i] == 1);
  unsigned long long m = __ballot(need);
  int wave = threadIdx.x >> 6;
  int lane = threadIdx.x & 63;
  if (lane == 0) wb[wave] = __popcll(m);
  __syncthreads();
  if (threadIdx.x == 0) {
    int t0 = wb[0], t1 = wb[1], t2 = wb[2], t3 = wb[3];
    int tot = t0 + t1 + t2 + t3;
    int base = tot ? atomicAdd(ccount, tot) : 0;
    wb[0] = base;
    wb[1] = base + t0;
    wb[2] = base + t0 + t1;
    wb[3] = base + t0 + t1 + t2;
  }
  __syncthreads();
  if (need) {
    int slot = wb[wave] + __popcll(m & ((1ull << lane) - 1ull));
    map[i] = slot;
    inv[slot] = i;
  }
}

// ===========================================================================
// K4 mega: 4 GEMMs + AP-CSR remap slice.
// XOR-swizzled W fragment layout (R5, keeps staging conflict-free).
// NEW: ONE tile per block (3541 gemm blocks -> no multi-tile serialization,
// no straggler tail) and X row-loads ISSUED BEFORE W staging so the
// ~800cy gather latency hides under staging + barrier.
// ===========================================================================
struct GemmJob {
  const float* X; const int* inv; const int* rowsp; int M;
  const float* W; const float* bias; unsigned short* Y; int nb;
};

__device__ __forceinline__ void gemm_body(const GemmJob& J, int bid, short8* lwb)
{
  const int tid = threadIdx.x;
  const int rows = J.rowsp ? *J.rowsp : J.M;
  const int wave = tid >> 6;
  const int lane = tid & 63;
  const int quad = lane >> 4;
  const int l16  = lane & 15;

  // ---- issue first tile's X loads BEFORE W staging (latency overlap) ----
  int tile = bid;
  long xrow = -1;
  float4 xa[4], xb[4];
  {
    int ra = tile * 64 + wave * 16 + l16;
    if (ra < rows) xrow = J.inv ? (long)J.inv[ra] : (long)ra;
    if (xrow >= 0) {
#pragma unroll
      for (int kt = 0; kt < 4; ++kt) {
        const float* p = J.X + xrow * 128 + kt * 32 + quad * 8;
        xa[kt] = ((const float4*)p)[0];
        xb[kt] = ((const float4*)p)[1];
      }
    }
  }

  // ---- W staging: coalesced float4 loads, swizzled scatter ----
  {
    unsigned short* lw16 = (unsigned short*)lwb;
#pragma unroll
    for (int p = 0; p < 16; ++p) {
      int fi = p * 1024 + tid * 4;
      float4 w4 = *(const float4*)(J.W + fi);
#pragma unroll
      for (int q = 0; q < 4; ++q) {
        int k = (fi + q) >> 7, n = (fi + q) & 127;
        float wv = (q == 0) ? w4.x : (q == 1) ? w4.y : (q == 2) ? w4.z : w4.w;
        int e = ((k >> 5) * 8 + (n >> 4)) * 64 + ((k >> 3) & 3) * 16 + (n & 15);
        e ^= (e >> 6) & 7;   // bank swizzle
        lw16[e * 8 + (k & 7)] = f2bf(wv);
      }
    }
  }
  __syncthreads();

  for (; tile * 64 < rows; tile += J.nb) {
    int ra = tile * 64 + wave * 16 + l16;   // this lane's X/Y row
    if (tile != bid) {
      // grid-stride overflow tile (practically never taken): reload X
      xrow = -1;
      if (ra < rows) xrow = J.inv ? (long)J.inv[ra] : (long)ra;
      if (xrow >= 0) {
#pragma unroll
        for (int kt = 0; kt < 4; ++kt) {
          const float* p = J.X + xrow * 128 + kt * 32 + quad * 8;
          xa[kt] = ((const float4*)p)[0];
          xb[kt] = ((const float4*)p)[1];
        }
      }
    }

    short8 xf[4];   // B operand: B[k = quad*8+j][n = l16] = X[row][k]
#pragma unroll
    for (int kt = 0; kt < 4; ++kt) {
      short8 a = {};
      if (xrow >= 0) {
        a[0] = (short)f2bf(xa[kt].x); a[1] = (short)f2bf(xa[kt].y);
        a[2] = (short)f2bf(xa[kt].z); a[3] = (short)f2bf(xa[kt].w);
        a[4] = (short)f2bf(xb[kt].x); a[5] = (short)f2bf(xb[kt].y);
        a[6] = (short)f2bf(xb[kt].z); a[7] = (short)f2bf(xb[kt].w);
      }
      xf[kt] = a;
    }

    f32x4 accs[8];
#pragma unroll
    for (int nt = 0; nt < 8; ++nt) {
      f32x4 acc = {0.f, 0.f, 0.f, 0.f};
#pragma unroll
      for (int kt = 0; kt < 4; ++kt)
        acc = __builtin_amdgcn_mfma_f32_16x16x32_bf16(
            lwb[(kt * 8 + nt) * 64 + (lane ^ nt)], xf[kt], acc, 0, 0, 0);
      accs[nt] = acc;  // D: lane l16 = X row, col = nt*16 + quad*4 + r
    }

    if (ra < rows) {
      unsigned short* yp = J.Y + (long)ra * 128;
#pragma unroll
      for (int nt = 0; nt < 8; ++nt) {
        int col = nt * 16 + quad * 4;
        float4 bv = *(const float4*)(J.bias + col);
        ushort4_t v;
        v[0] = f2bf(accs[nt][0] + bv.x);
        v[1] = f2bf(accs[nt][1] + bv.y);
        v[2] = f2bf(accs[nt][2] + bv.z);
        v[3] = f2bf(accs[nt][3] + bv.w);
        *(ushort4_t*)(yp + col) = v;
      }
    }
  }
}

__global__ __launch_bounds__(256) void k_mega(
    GemmJob j0, GemmJob j1, GemmJob j2, GemmJob j3,
    const int* __restrict__ map, const int* __restrict__ cnt_ap,
    int* __restrict__ csr_ap, int nb_gemm, int nb_remap, int batch)
{
  __shared__ short8 lwb[4 * 8 * 64];   // exactly 32 KB
  int b = blockIdx.x;
  if (b < nb_gemm) {
    if (b < j0.nb)                      gemm_body(j0, b, lwb);
    else if (b < j0.nb + j1.nb)         gemm_body(j1, b - j0.nb, lwb);
    else if (b < j0.nb + j1.nb + j2.nb) gemm_body(j2, b - j0.nb - j1.nb, lwb);
    else                                gemm_body(j3, b - j0.nb - j1.nb - j2.nb, lwb);
  } else {
    // remap AP CSR entries: original src -> compact row (single indirection in K5)
    int i = (b - nb_gemm) * 256 + threadIdx.x;
    if (i < batch * CAP_AP) {
      int d = i / CAP_AP;
      int slot = i - d * CAP_AP;
      int n = cnt_ap[d]; if (n > CAP_AP) n = CAP_AP;
      if (slot < n) csr_ap[i] = map[csr_ap[i]];
    }
  }
}

// ===========================================================================
// K5: fused per-dst GATv2 (both types) + relu + W_lin head -> out.
// One wave/dst, FOUR 16-lane groups = 4 edges in flight, 8 ch/lane (16B
// loads), 4-level intra-group shfl reduce, double-buffered csr+xl prefetch.
// (R3 version — known good.)
// ===========================================================================
__global__ __launch_bounds__(256) void k_gat_final(
    const int* __restrict__ cnt_ap, const int* __restrict__ csr_ap,
    const unsigned short* __restrict__ xl_aa,
    const unsigned short* __restrict__ xr_ap, const float* __restrict__ att_ap,
    const int* __restrict__ cnt_pp, const int* __restrict__ csr_pp,
    const unsigned short* __restrict__ xl_pp,
    const unsigned short* __restrict__ xr_pp, const float* __restrict__ att_pp,
    const float* __restrict__ bias_ap, const float* __restrict__ bias_pp,
    const float* __restrict__ W_lin, const float* __restrict__ b_lin,
    float* __restrict__ out, int batch)
{
  __shared__ unsigned lw2[64 * 64];  // 16 KB: [cpair][ocol] packed bf16x2
  __shared__ float lh[4][128];       // 2 KB
  for (int e = threadIdx.x; e < 4096; e += 256) {
    int cp = e >> 6, o = e & 63;
    unsigned lo = f2bf(W_lin[(2 * cp) * 64 + o]);
    unsigned hi = f2bf(W_lin[(2 * cp + 1) * 64 + o]);
    lw2[e] = lo | (hi << 16);
  }

  const int wave = threadIdx.x >> 6;
  const int lane = threadIdx.x & 63;
  const int g    = lane >> 4;      // edge group within wave
  const int l16  = lane & 15;
  const int cb   = l16 * 8;        // this lane's 8 channels
  const int dst  = blockIdx.x * 4 + wave;

  float h[8];
  if (dst < batch) {
    {
      float4 ba0 = *(const float4*)(bias_ap + cb);
      float4 ba1 = *(const float4*)(bias_ap + cb + 4);
      float4 bp0 = *(const float4*)(bias_pp + cb);
      float4 bp1 = *(const float4*)(bias_pp + cb + 4);
      h[0] = ba0.x + bp0.x; h[1] = ba0.y + bp0.y;
      h[2] = ba0.z + bp0.z; h[3] = ba0.w + bp0.w;
      h[4] = ba1.x + bp1.x; h[5] = ba1.y + bp1.y;
      h[6] = ba1.z + bp1.z; h[7] = ba1.w + bp1.w;
    }

#pragma unroll
    for (int type = 0; type < 2; ++type) {
      const int* cnt  = type ? cnt_pp : cnt_ap;
      const int* csr  = type ? csr_pp : csr_ap;
      const int cap   = type ? CAP_PP : CAP_AP;
      const unsigned short* xl = type ? xl_pp : xl_aa;
      const unsigned short* xr = type ? xr_pp : xr_ap;
      const float* att = type ? att_pp : att_ap;

      int n = __builtin_amdgcn_readfirstlane(cnt[dst]);
      if (n > cap) n = cap;
      const long base = (long)dst * cap;

      float xrv[8], atv[8];
      {
        short8 uxr = *(const short8*)(xr + (long)dst * 128 + cb);
#pragma unroll
        for (int k = 0; k < 8; ++k)
          xrv[k] = __uint_as_float(((unsigned)(unsigned short)uxr[k]) << 16);
        float4 a0 = *(const float4*)(att + cb);
        float4 a1 = *(const float4*)(att + cb + 4);
        atv[0] = a0.x; atv[1] = a0.y; atv[2] = a0.z; atv[3] = a0.w;
        atv[4] = a1.x; atv[5] = a1.y; atv[6] = a1.z; atv[7] = a1.w;
      }

      float l = 0.f, o[8];
#pragma unroll
      for (int k = 0; k < 8; ++k) o[k] = 0.f;

      if (n > 0) {
        // prefetch group-edge 0
        bool act = g < n;
        int si = act ? csr[base + g] : 0;
        short8 ua = *(const short8*)(xl + (long)si * 128 + cb);
        int niter = (n + 3) >> 2;
        for (int it = 0; it < niter; ++it) {
          // prefetch next 4-edge group while processing current
          int en = it * 4 + 4 + g;
          bool actn = en < n;
          int sin = actn ? csr[base + en] : 0;
          short8 uan = *(const short8*)(xl + (long)sin * 128 + cb);

          float a[8];
#pragma unroll
          for (int k = 0; k < 8; ++k)
            a[k] = __uint_as_float(((unsigned)(unsigned short)ua[k]) << 16);
          float p = 0.f;
#pragma unroll
          for (int k = 0; k < 8; ++k) {
            float e = a[k] + xrv[k];
            e = e > 0.f ? e : 0.2f * e;
            p = fmaf(atv[k], e, p);
          }
          // reduce logit within the 16-lane group (xor bits < 4 stay in group)
          p += __shfl_xor(p, 8, 64);
          p += __shfl_xor(p, 4, 64);
          p += __shfl_xor(p, 2, 64);
          p += __shfl_xor(p, 1, 64);
          float w = act ? __expf(p) : 0.f;
          l += w;
#pragma unroll
          for (int k = 0; k < 8; ++k) o[k] = fmaf(w, a[k], o[k]);

          ua = uan; act = actn;
        }
      }
      // merge the 4 groups' partial denominators/numerators (butterfly)
      l += __shfl_xor(l, 16, 64);
      l += __shfl_xor(l, 32, 64);
#pragma unroll
      for (int k = 0; k < 8; ++k) {
        o[k] += __shfl_xor(o[k], 16, 64);
        o[k] += __shfl_xor(o[k], 32, 64);
      }
      float invl = (l > 0.f) ? 1.f / l : 0.f;
#pragma unroll
      for (int k = 0; k < 8; ++k) h[k] = fmaf(o[k], invl, h[k]);
    }
  } else {
#pragma unroll
    for (int k = 0; k < 8; ++k) h[k] = 0.f;
  }

  if (g == 0) {
    float4 r0, r1;
    r0.x = h[0] > 0.f ? h[0] : 0.f; r0.y = h[1] > 0.f ? h[1] : 0.f;
    r0.z = h[2] > 0.f ? h[2] : 0.f; r0.w = h[3] > 0.f ? h[3] : 0.f;
    r1.x = h[4] > 0.f ? h[4] : 0.f; r1.y = h[5] > 0.f ? h[5] : 0.f;
    r1.z = h[6] > 0.f ? h[6] : 0.f; r1.w = h[7] > 0.f ? h[7] : 0.f;
    *(float4*)&lh[wave][cb]     = r0;
    *(float4*)&lh[wave][cb + 4] = r1;
  }
  __syncthreads();

  if (dst < batch) {
    float acc = b_lin[lane];
#pragma unroll 16
    for (int cp = 0; cp < 64; ++cp) {
      unsigned u = lw2[cp * 64 + lane];
      acc = fmaf(lh[wave][2 * cp],     __uint_as_float(u << 16),        acc);
      acc = fmaf(lh[wave][2 * cp + 1], __uint_as_float(u & 0xffff0000u), acc);
    }
    out[(long)dst * 64 + lane] = acc;
  }
}

// ===========================================================================
extern "C" void kernel_launch(void* const* d_in, const int* in_sizes, int n_in,
                              void* d_out, int out_size, void* d_ws, size_t ws_size,
                              hipStream_t stream)
{
  const float* x_aa   = (const float*)d_in[0];
  const float* x_prot = (const float*)d_in[1];
  const int*   ei_ap  = (const int*)d_in[2];
  const int*   ei_pp  = (const int*)d_in[3];
  const float* Wl_ap  = (const float*)d_in[5];
  const float* bl_ap  = (const float*)d_in[6];
  const float* Wr_ap  = (const float*)d_in[7];
  const float* br_ap  = (const float*)d_in[8];
  const float* att_ap = (const float*)d_in[9];
  const float* bias_ap= (const float*)d_in[10];
  const float* Wl_pp  = (const float*)d_in[11];
  const float* bl_pp  = (const float*)d_in[12];
  const float* Wr_pp  = (const float*)d_in[13];
  const float* br_pp  = (const float*)d_in[14];
  const float* att_pp = (const float*)d_in[15];
  const float* bias_pp= (const float*)d_in[16];
  const float* W_lin  = (const float*)d_in[17];
  const float* b_lin  = (const float*)d_in[18];
  float* out = (float*)d_out;

  const int D = 128;
  const int n_aa   = in_sizes[0] / D;
  const int n_prot = in_sizes[1] / D;
  const int e_ap   = in_sizes[2] / 2;
  const int e_pp   = in_sizes[3] / 2;
  const int batch  = out_size / 64;   // 16384

  char* p = (char*)d_ws;
  auto take = [&](size_t n) { char* r = p; p += (n + 255) & ~(size_t)255; return r; };
  unsigned short* xlc_aa = (unsigned short*)take((size_t)n_aa * D * 2);
  unsigned short* xl_pp  = (unsigned short*)take((size_t)n_prot * D * 2);
  unsigned short* xr_ap  = (unsigned short*)take((size_t)batch * D * 2);
  unsigned short* xr_pp  = (unsigned short*)take((size_t)batch * D * 2);
  int* map      = (int*)take((size_t)n_aa * 4);
  int* inv      = (int*)take((size_t)n_aa * 4);
  int* ccount   = (int*)take(4);
  int* cnt_ap   = (int*)take((size_t)batch * 4);
  int* cnt_pp   = (int*)take((size_t)batch * 4);
  int* csr_ap   = (int*)take((size_t)batch * CAP_AP * 4);
  int* csr_pp   = (int*)take((size_t)batch * CAP_PP * 4);
  (void)ws_size; (void)n_in;

  const int nb_ap = (e_ap + 255) / 256;
  const int nb_pp = (e_pp + 255) / 256;
  const int nb_init = (n_aa + 255) / 256;

  k_init<<<nb_init, 256, 0, stream>>>(map, cnt_ap, cnt_pp, ccount, n_aa, batch);
  k_edges<<<nb_ap + nb_pp, 256, 0, stream>>>(
      ei_ap, ei_pp, map, cnt_ap, cnt_pp, csr_ap, csr_pp,
      e_ap, e_pp, nb_ap, batch);
  k_assign<<<nb_init, 256, 0, stream>>>(map, inv, ccount, n_aa);

  // ONE tile per block: j0 sized for worst-case compact count (grid-stride
  // loop retained as safety), j1/j2/j3 exact.
  GemmJob j0{x_aa,   inv,     ccount,  0,      Wl_ap, bl_ap, xlc_aa, 2560};
  GemmJob j1{x_prot, nullptr, nullptr, n_prot, Wl_pp, bl_pp, xl_pp,  (n_prot + 63) / 64};
  GemmJob j2{x_prot, nullptr, nullptr, batch,  Wr_ap, br_ap, xr_ap,  (batch + 63) / 64};
  GemmJob j3{x_prot, nullptr, nullptr, batch,  Wr_pp, br_pp, xr_pp,  (batch + 63) / 64};
  const int nb_gemm = j0.nb + j1.nb + j2.nb + j3.nb;
  const int nb_remap = (batch * CAP_AP + 255) / 256;
  k_mega<<<nb_gemm + nb_remap, 256, 0, stream>>>(
      j0, j1, j2, j3, map, cnt_ap, csr_ap, nb_gemm, nb_remap, batch);

  k_gat_final<<<(batch + 3) / 4, 256, 0, stream>>>(
      cnt_ap, csr_ap, xlc_aa, xr_ap, att_ap,
      cnt_pp, csr_pp, xl_pp, xr_pp, att_pp,
      bias_ap, bias_pp, W_lin, b_lin, out, batch);
}

// Round 7
// 408.283 us; speedup vs baseline: 1.0263x; 1.0263x over previous
//
#include <hip/hip_runtime.h>
#include <hip/hip_bf16.h>

typedef __attribute__((ext_vector_type(8))) short short8;
typedef __attribute__((ext_vector_type(4))) unsigned short ushort4_t;
typedef __attribute__((ext_vector_type(4))) float f32x4;

#define CAP_AP 64
#define CAP_PP 128

__device__ __forceinline__ unsigned short f2bf(float f) {
  unsigned u = __float_as_uint(f);
  u += 0x7FFFu + ((u >> 16) & 1u);
  return (unsigned short)(u >> 16);
}

// ===========================================================================
// K1: init map / counters
// ===========================================================================
__global__ __launch_bounds__(256) void k_init(
    int* __restrict__ map, int* __restrict__ cnt_ap, int* __restrict__ cnt_pp,
    int* __restrict__ ccount, int n_aa, int batch)
{
  int i = blockIdx.x * 256 + threadIdx.x;
  if (i < n_aa) map[i] = -1;
  if (i < batch) { cnt_ap[i] = 0; cnt_pp[i] = 0; }
  if (i == 0) *ccount = 0;
}

// ===========================================================================
// K2: histogram + DIRECT bucket-CSR fill (no scan/scatter passes needed).
// ===========================================================================
__global__ __launch_bounds__(256) void k_edges(
    const int* __restrict__ ei_ap, const int* __restrict__ ei_pp,
    int* __restrict__ map, int* __restrict__ cnt_ap, int* __restrict__ cnt_pp,
    int* __restrict__ csr_ap, int* __restrict__ csr_pp,
    int e_ap, int e_pp, int nb_ap, int batch)
{
  int b = blockIdx.x;
  if (b < nb_ap) {
    int e = b * 256 + threadIdx.x;
    if (e < e_ap) {
      int d = ei_ap[e_ap + e];
      if (d < batch) {
        int s = ei_ap[e];
        int pos = atomicAdd(&cnt_ap[d], 1);
        if (pos < CAP_AP) csr_ap[d * CAP_AP + pos] = s;
        map[s] = 1;
      }
    }
  } else {
    int e = (b - nb_ap) * 256 + threadIdx.x;
    if (e < e_pp) {
      int d = ei_pp[e_pp + e];
      if (d < batch) {
        int pos = atomicAdd(&cnt_pp[d], 1);
        if (pos < CAP_PP) csr_pp[d * CAP_PP + pos] = ei_pp[e];
      }
    }
  }
}

// ===========================================================================
// K3: compaction-slot assignment, block-aggregated atomic (1 atomic/block).
// ===========================================================================
__global__ __launch_bounds__(256) void k_assign(
    int* __restrict__ map, int* __restrict__ inv, int* __restrict__ ccount, int n)
{
  __shared__ int wb[4];
  int i = blockIdx.x * 256 + threadIdx.x;
  bool need = (i < n) && (map[i] == 1);
  unsigned long long m = __ballot(need);
  int wave = threadIdx.x >> 6;
  int lane = threadIdx.x & 63;
  if (lane == 0) wb[wave] = __popcll(m);
  __syncthreads();
  if (threadIdx.x == 0) {
    int t0 = wb[0], t1 = wb[1], t2 = wb[2], t3 = wb[3];
    int tot = t0 + t1 + t2 + t3;
    int base = tot ? atomicAdd(ccount, tot) : 0;
    wb[0] = base;
    wb[1] = base + t0;
    wb[2] = base + t0 + t1;
    wb[3] = base + t0 + t1 + t2;
  }
  __syncthreads();
  if (need) {
    int slot = wb[wave] + __popcll(m & ((1ull << lane) - 1ull));
    map[i] = slot;
    inv[slot] = i;
  }
}

// ===========================================================================
// K4 mega: 4 GEMMs + AP-CSR remap slice.
// XOR-swizzled W fragment layout (conflict-free staging, proven R5).
// R5 block counts (1024 blocks -> ONE W staging per block, 2-5 tiles each)
// + NEW cross-tile X double-buffer: tile t+1's inv+X loads issue before
// tile t's convert/MFMA/store, hiding the ~800cy gather under compute.
// ===========================================================================
struct GemmJob {
  const float* X; const int* inv; const int* rowsp; int M;
  const float* W; const float* bias; unsigned short* Y; int nb;
};

__device__ __forceinline__ void gemm_body(const GemmJob& J, int bid, short8* lwb)
{
  const int tid = threadIdx.x;
  const int rows = J.rowsp ? *J.rowsp : J.M;
  const int wave = tid >> 6;
  const int lane = tid & 63;
  const int quad = lane >> 4;
  const int l16  = lane & 15;

  // ---- issue tile 0's X loads BEFORE W staging (overlaps with staging) ----
  int tile = bid;
  long xrow = -1;
  float4 xa[4], xb[4];
  {
    int ra = tile * 64 + wave * 16 + l16;
    if (ra < rows) xrow = J.inv ? (long)J.inv[ra] : (long)ra;
    if (xrow >= 0) {
#pragma unroll
      for (int kt = 0; kt < 4; ++kt) {
        const float* p = J.X + xrow * 128 + kt * 32 + quad * 8;
        xa[kt] = ((const float4*)p)[0];
        xb[kt] = ((const float4*)p)[1];
      }
    }
  }

  // ---- W staging: coalesced float4 loads, swizzled scatter ----
  {
    unsigned short* lw16 = (unsigned short*)lwb;
#pragma unroll
    for (int p = 0; p < 16; ++p) {
      int fi = p * 1024 + tid * 4;
      float4 w4 = *(const float4*)(J.W + fi);
#pragma unroll
      for (int q = 0; q < 4; ++q) {
        int k = (fi + q) >> 7, n = (fi + q) & 127;
        float wv = (q == 0) ? w4.x : (q == 1) ? w4.y : (q == 2) ? w4.z : w4.w;
        int e = ((k >> 5) * 8 + (n >> 4)) * 64 + ((k >> 3) & 3) * 16 + (n & 15);
        e ^= (e >> 6) & 7;   // bank swizzle
        lw16[e * 8 + (k & 7)] = f2bf(wv);
      }
    }
  }
  __syncthreads();

  while (tile * 64 < rows) {
    const int ra = tile * 64 + wave * 16 + l16;   // current tile's X/Y row
    const int tnext = tile + J.nb;

    // ---- prefetch NEXT tile's X while we convert/MFMA/store current ----
    long xrow_n = -1;
    float4 na[4], nb4[4];
    if (tnext * 64 < rows) {
      int rn = tnext * 64 + wave * 16 + l16;
      if (rn < rows) xrow_n = J.inv ? (long)J.inv[rn] : (long)rn;
      if (xrow_n >= 0) {
#pragma unroll
        for (int kt = 0; kt < 4; ++kt) {
          const float* p = J.X + xrow_n * 128 + kt * 32 + quad * 8;
          na[kt]  = ((const float4*)p)[0];
          nb4[kt] = ((const float4*)p)[1];
        }
      }
    }

    short8 xf[4];   // B operand: B[k = quad*8+j][n = l16] = X[row][k]
#pragma unroll
    for (int kt = 0; kt < 4; ++kt) {
      short8 a = {};
      if (xrow >= 0) {
        a[0] = (short)f2bf(xa[kt].x); a[1] = (short)f2bf(xa[kt].y);
        a[2] = (short)f2bf(xa[kt].z); a[3] = (short)f2bf(xa[kt].w);
        a[4] = (short)f2bf(xb[kt].x); a[5] = (short)f2bf(xb[kt].y);
        a[6] = (short)f2bf(xb[kt].z); a[7] = (short)f2bf(xb[kt].w);
      }
      xf[kt] = a;
    }

    f32x4 accs[8];
#pragma unroll
    for (int nt = 0; nt < 8; ++nt) {
      f32x4 acc = {0.f, 0.f, 0.f, 0.f};
#pragma unroll
      for (int kt = 0; kt < 4; ++kt)
        acc = __builtin_amdgcn_mfma_f32_16x16x32_bf16(
            lwb[(kt * 8 + nt) * 64 + (lane ^ nt)], xf[kt], acc, 0, 0, 0);
      accs[nt] = acc;  // D: lane l16 = X row, col = nt*16 + quad*4 + r
    }

    if (ra < rows) {
      unsigned short* yp = J.Y + (long)ra * 128;
#pragma unroll
      for (int nt = 0; nt < 8; ++nt) {
        int col = nt * 16 + quad * 4;
        float4 bv = *(const float4*)(J.bias + col);
        ushort4_t v;
        v[0] = f2bf(accs[nt][0] + bv.x);
        v[1] = f2bf(accs[nt][1] + bv.y);
        v[2] = f2bf(accs[nt][2] + bv.z);
        v[3] = f2bf(accs[nt][3] + bv.w);
        *(ushort4_t*)(yp + col) = v;
      }
    }

    // rotate double buffer
    xrow = xrow_n;
#pragma unroll
    for (int kt = 0; kt < 4; ++kt) { xa[kt] = na[kt]; xb[kt] = nb4[kt]; }
    tile = tnext;
  }
}

__global__ __launch_bounds__(256) void k_mega(
    GemmJob j0, GemmJob j1, GemmJob j2, GemmJob j3,
    const int* __restrict__ map, const int* __restrict__ cnt_ap,
    int* __restrict__ csr_ap, int nb_gemm, int nb_remap, int batch)
{
  __shared__ short8 lwb[4 * 8 * 64];   // exactly 32 KB
  int b = blockIdx.x;
  if (b < nb_gemm) {
    if (b < j0.nb)                      gemm_body(j0, b, lwb);
    else if (b < j0.nb + j1.nb)         gemm_body(j1, b - j0.nb, lwb);
    else if (b < j0.nb + j1.nb + j2.nb) gemm_body(j2, b - j0.nb - j1.nb, lwb);
    else                                gemm_body(j3, b - j0.nb - j1.nb - j2.nb, lwb);
  } else {
    // remap AP CSR entries: original src -> compact row (single indirection in K5)
    int i = (b - nb_gemm) * 256 + threadIdx.x;
    if (i < batch * CAP_AP) {
      int d = i / CAP_AP;
      int slot = i - d * CAP_AP;
      int n = cnt_ap[d]; if (n > CAP_AP) n = CAP_AP;
      if (slot < n) csr_ap[i] = map[csr_ap[i]];
    }
  }
}

// ===========================================================================
// K5: fused per-dst GATv2 (both types) + relu + W_lin head -> out.
// One wave/dst, FOUR 16-lane groups = 4 edges in flight, 8 ch/lane (16B
// loads), 4-level intra-group shfl reduce, double-buffered csr+xl prefetch.
// (R3 version — known good.)
// ===========================================================================
__global__ __launch_bounds__(256) void k_gat_final(
    const int* __restrict__ cnt_ap, const int* __restrict__ csr_ap,
    const unsigned short* __restrict__ xl_aa,
    const unsigned short* __restrict__ xr_ap, const float* __restrict__ att_ap,
    const int* __restrict__ cnt_pp, const int* __restrict__ csr_pp,
    const unsigned short* __restrict__ xl_pp,
    const unsigned short* __restrict__ xr_pp, const float* __restrict__ att_pp,
    const float* __restrict__ bias_ap, const float* __restrict__ bias_pp,
    const float* __restrict__ W_lin, const float* __restrict__ b_lin,
    float* __restrict__ out, int batch)
{
  __shared__ unsigned lw2[64 * 64];  // 16 KB: [cpair][ocol] packed bf16x2
  __shared__ float lh[4][128];       // 2 KB
  for (int e = threadIdx.x; e < 4096; e += 256) {
    int cp = e >> 6, o = e & 63;
    unsigned lo = f2bf(W_lin[(2 * cp) * 64 + o]);
    unsigned hi = f2bf(W_lin[(2 * cp + 1) * 64 + o]);
    lw2[e] = lo | (hi << 16);
  }

  const int wave = threadIdx.x >> 6;
  const int lane = threadIdx.x & 63;
  const int g    = lane >> 4;      // edge group within wave
  const int l16  = lane & 15;
  const int cb   = l16 * 8;        // this lane's 8 channels
  const int dst  = blockIdx.x * 4 + wave;

  float h[8];
  if (dst < batch) {
    {
      float4 ba0 = *(const float4*)(bias_ap + cb);
      float4 ba1 = *(const float4*)(bias_ap + cb + 4);
      float4 bp0 = *(const float4*)(bias_pp + cb);
      float4 bp1 = *(const float4*)(bias_pp + cb + 4);
      h[0] = ba0.x + bp0.x; h[1] = ba0.y + bp0.y;
      h[2] = ba0.z + bp0.z; h[3] = ba0.w + bp0.w;
      h[4] = ba1.x + bp1.x; h[5] = ba1.y + bp1.y;
      h[6] = ba1.z + bp1.z; h[7] = ba1.w + bp1.w;
    }

#pragma unroll
    for (int type = 0; type < 2; ++type) {
      const int* cnt  = type ? cnt_pp : cnt_ap;
      const int* csr  = type ? csr_pp : csr_ap;
      const int cap   = type ? CAP_PP : CAP_AP;
      const unsigned short* xl = type ? xl_pp : xl_aa;
      const unsigned short* xr = type ? xr_pp : xr_ap;
      const float* att = type ? att_pp : att_ap;

      int n = __builtin_amdgcn_readfirstlane(cnt[dst]);
      if (n > cap) n = cap;
      const long base = (long)dst * cap;

      float xrv[8], atv[8];
      {
        short8 uxr = *(const short8*)(xr + (long)dst * 128 + cb);
#pragma unroll
        for (int k = 0; k < 8; ++k)
          xrv[k] = __uint_as_float(((unsigned)(unsigned short)uxr[k]) << 16);
        float4 a0 = *(const float4*)(att + cb);
        float4 a1 = *(const float4*)(att + cb + 4);
        atv[0] = a0.x; atv[1] = a0.y; atv[2] = a0.z; atv[3] = a0.w;
        atv[4] = a1.x; atv[5] = a1.y; atv[6] = a1.z; atv[7] = a1.w;
      }

      float l = 0.f, o[8];
#pragma unroll
      for (int k = 0; k < 8; ++k) o[k] = 0.f;

      if (n > 0) {
        // prefetch group-edge 0
        bool act = g < n;
        int si = act ? csr[base + g] : 0;
        short8 ua = *(const short8*)(xl + (long)si * 128 + cb);
        int niter = (n + 3) >> 2;
        for (int it = 0; it < niter; ++it) {
          // prefetch next 4-edge group while processing current
          int en = it * 4 + 4 + g;
          bool actn = en < n;
          int sin = actn ? csr[base + en] : 0;
          short8 uan = *(const short8*)(xl + (long)sin * 128 + cb);

          float a[8];
#pragma unroll
          for (int k = 0; k < 8; ++k)
            a[k] = __uint_as_float(((unsigned)(unsigned short)ua[k]) << 16);
          float p = 0.f;
#pragma unroll
          for (int k = 0; k < 8; ++k) {
            float e = a[k] + xrv[k];
            e = e > 0.f ? e : 0.2f * e;
            p = fmaf(atv[k], e, p);
          }
          // reduce logit within the 16-lane group (xor bits < 4 stay in group)
          p += __shfl_xor(p, 8, 64);
          p += __shfl_xor(p, 4, 64);
          p += __shfl_xor(p, 2, 64);
          p += __shfl_xor(p, 1, 64);
          float w = act ? __expf(p) : 0.f;
          l += w;
#pragma unroll
          for (int k = 0; k < 8; ++k) o[k] = fmaf(w, a[k], o[k]);

          ua = uan; act = actn;
        }
      }
      // merge the 4 groups' partial denominators/numerators (butterfly)
      l += __shfl_xor(l, 16, 64);
      l += __shfl_xor(l, 32, 64);
#pragma unroll
      for (int k = 0; k < 8; ++k) {
        o[k] += __shfl_xor(o[k], 16, 64);
        o[k] += __shfl_xor(o[k], 32, 64);
      }
      float invl = (l > 0.f) ? 1.f / l : 0.f;
#pragma unroll
      for (int k = 0; k < 8; ++k) h[k] = fmaf(o[k], invl, h[k]);
    }
  } else {
#pragma unroll
    for (int k = 0; k < 8; ++k) h[k] = 0.f;
  }

  if (g == 0) {
    float4 r0, r1;
    r0.x = h[0] > 0.f ? h[0] : 0.f; r0.y = h[1] > 0.f ? h[1] : 0.f;
    r0.z = h[2] > 0.f ? h[2] : 0.f; r0.w = h[3] > 0.f ? h[3] : 0.f;
    r1.x = h[4] > 0.f ? h[4] : 0.f; r1.y = h[5] > 0.f ? h[5] : 0.f;
    r1.z = h[6] > 0.f ? h[6] : 0.f; r1.w = h[7] > 0.f ? h[7] : 0.f;
    *(float4*)&lh[wave][cb]     = r0;
    *(float4*)&lh[wave][cb + 4] = r1;
  }
  __syncthreads();

  if (dst < batch) {
    float acc = b_lin[lane];
#pragma unroll 16
    for (int cp = 0; cp < 64; ++cp) {
      unsigned u = lw2[cp * 64 + lane];
      acc = fmaf(lh[wave][2 * cp],     __uint_as_float(u << 16),        acc);
      acc = fmaf(lh[wave][2 * cp + 1], __uint_as_float(u & 0xffff0000u), acc);
    }
    out[(long)dst * 64 + lane] = acc;
  }
}

// ===========================================================================
extern "C" void kernel_launch(void* const* d_in, const int* in_sizes, int n_in,
                              void* d_out, int out_size, void* d_ws, size_t ws_size,
                              hipStream_t stream)
{
  const float* x_aa   = (const float*)d_in[0];
  const float* x_prot = (const float*)d_in[1];
  const int*   ei_ap  = (const int*)d_in[2];
  const int*   ei_pp  = (const int*)d_in[3];
  const float* Wl_ap  = (const float*)d_in[5];
  const float* bl_ap  = (const float*)d_in[6];
  const float* Wr_ap  = (const float*)d_in[7];
  const float* br_ap  = (const float*)d_in[8];
  const float* att_ap = (const float*)d_in[9];
  const float* bias_ap= (const float*)d_in[10];
  const float* Wl_pp  = (const float*)d_in[11];
  const float* bl_pp  = (const float*)d_in[12];
  const float* Wr_pp  = (const float*)d_in[13];
  const float* br_pp  = (const float*)d_in[14];
  const float* att_pp = (const float*)d_in[15];
  const float* bias_pp= (const float*)d_in[16];
  const float* W_lin  = (const float*)d_in[17];
  const float* b_lin  = (const float*)d_in[18];
  float* out = (float*)d_out;

  const int D = 128;
  const int n_aa   = in_sizes[0] / D;
  const int n_prot = in_sizes[1] / D;
  const int e_ap   = in_sizes[2] / 2;
  const int e_pp   = in_sizes[3] / 2;
  const int batch  = out_size / 64;   // 16384

  char* p = (char*)d_ws;
  auto take = [&](size_t n) { char* r = p; p += (n + 255) & ~(size_t)255; return r; };
  unsigned short* xlc_aa = (unsigned short*)take((size_t)n_aa * D * 2);
  unsigned short* xl_pp  = (unsigned short*)take((size_t)n_prot * D * 2);
  unsigned short* xr_ap  = (unsigned short*)take((size_t)batch * D * 2);
  unsigned short* xr_pp  = (unsigned short*)take((size_t)batch * D * 2);
  int* map      = (int*)take((size_t)n_aa * 4);
  int* inv      = (int*)take((size_t)n_aa * 4);
  int* ccount   = (int*)take(4);
  int* cnt_ap   = (int*)take((size_t)batch * 4);
  int* cnt_pp   = (int*)take((size_t)batch * 4);
  int* csr_ap   = (int*)take((size_t)batch * CAP_AP * 4);
  int* csr_pp   = (int*)take((size_t)batch * CAP_PP * 4);
  (void)ws_size; (void)n_in;

  const int nb_ap = (e_ap + 255) / 256;
  const int nb_pp = (e_pp + 255) / 256;
  const int nb_init = (n_aa + 255) / 256;

  k_init<<<nb_init, 256, 0, stream>>>(map, cnt_ap, cnt_pp, ccount, n_aa, batch);
  k_edges<<<nb_ap + nb_pp, 256, 0, stream>>>(
      ei_ap, ei_pp, map, cnt_ap, cnt_pp, csr_ap, csr_pp,
      e_ap, e_pp, nb_ap, batch);
  k_assign<<<nb_init, 256, 0, stream>>>(map, inv, ccount, n_aa);

  // 1024 gemm blocks (R5 config): each stages W ONCE, loops 2-5 tiles with
  // cross-tile X prefetch.
  GemmJob j0{x_aa,   inv,     ccount,  0,      Wl_ap, bl_ap, xlc_aa, 512};
  GemmJob j1{x_prot, nullptr, nullptr, n_prot, Wl_pp, bl_pp, xl_pp,  256};
  GemmJob j2{x_prot, nullptr, nullptr, batch,  Wr_ap, br_ap, xr_ap,  128};
  GemmJob j3{x_prot, nullptr, nullptr, batch,  Wr_pp, br_pp, xr_pp,  128};
  const int nb_gemm = j0.nb + j1.nb + j2.nb + j3.nb;
  const int nb_remap = (batch * CAP_AP + 255) / 256;
  k_mega<<<nb_gemm + nb_remap, 256, 0, stream>>>(
      j0, j1, j2, j3, map, cnt_ap, csr_ap, nb_gemm, nb_remap, batch);

  k_gat_final<<<(batch + 3) / 4, 256, 0, stream>>>(
      cnt_ap, csr_ap, xlc_aa, xr_ap, att_ap,
      cnt_pp, csr_pp, xl_pp, xr_pp, att_pp,
      bias_ap, bias_pp, W_lin, b_lin, out, batch);
}